// Round 9
// baseline (263.181 us; speedup 1.0000x reference)
//
#include <hip/hip_runtime.h>

#define N_NODES 50000
#define N_EDGES 800000
#define N_PAIRS 8192
#define N_SLOTS (2 * N_PAIRS)
#define CAP     64          // per-node bucket capacity; P(deg>63)~5e-19

// Sinkhorn constants (log2 domain):
//   C2 = -(C/eps + ln32)*log2e ; potentials kept in /(eps*ln2) units
#define INV_EPS   20.0f
#define LOG2E_F   1.4426950408889634f
#define LN2_F     0.6931471805599453f
#define LN32_F    3.4657359027997265f
#define EPS_F     0.05f

typedef float f2 __attribute__((ext_vector_type(2)));

// ---------------------------------------------------------------- mark needed
__global__ void k_mark(const int* __restrict__ pairs, int* __restrict__ flags) {
    int t = blockIdx.x * 256 + threadIdx.x;
    if (t < N_SLOTS) flags[pairs[t]] = 1;
}

// ---------------------------------------- scatter into fixed-cap buckets
__global__ __launch_bounds__(256) void k_scatter(
        const int* __restrict__ eidx, const int* __restrict__ flags,
        int* __restrict__ cnt, int* __restrict__ bucket) {
    int t = blockIdx.x * 256 + threadIdx.x;   // exact grid: 800000/256
    int dst = eidx[N_EDGES + t];
    if (!flags[dst]) return;
    int pos = atomicAdd(&cnt[dst], 1);
    if (pos < CAP) bucket[dst * CAP + pos] = eidx[t];
}

// ------------------------------------ fused gather + GEMM + relu
__global__ __launch_bounds__(256) void k_gemm(
        const int* __restrict__ pairs, const float* __restrict__ x,
        const int* __restrict__ cnt, const int* __restrict__ bucket,
        const float* __restrict__ W, float* __restrict__ Z) {
    __shared__ __align__(16) float Us[16 * 128];
    int sbase = blockIdx.x * 16;
    int t = threadIdx.x;
    int wave = t >> 6, lane = t & 63;

    #pragma unroll
    for (int rr = 0; rr < 4; ++rr) {
        int r = wave * 4 + rr;
        int node = pairs[sbase + r];
        int n = cnt[node];
        int m = (n < CAP) ? n : CAP;
        const int* bk = bucket + node * CAP;
        float ax = 0.0f, ay = 0.0f;
        int k = 0;
        for (; k + 4 <= m; k += 4) {
            int s0 = bk[k], s1 = bk[k + 1], s2 = bk[k + 2], s3 = bk[k + 3];
            float2 v0 = *(const float2*)(x + (size_t)s0 * 128 + lane * 2);
            float2 v1 = *(const float2*)(x + (size_t)s1 * 128 + lane * 2);
            float2 v2 = *(const float2*)(x + (size_t)s2 * 128 + lane * 2);
            float2 v3 = *(const float2*)(x + (size_t)s3 * 128 + lane * 2);
            ax += (v0.x + v1.x) + (v2.x + v3.x);
            ay += (v0.y + v1.y) + (v2.y + v3.y);
        }
        for (; k < m; ++k) {
            int s0 = bk[k];
            float2 v0 = *(const float2*)(x + (size_t)s0 * 128 + lane * 2);
            ax += v0.x;
            ay += v0.y;
        }
        float rdeg = 1.0f / fmaxf((float)n, 1.0f);
        float2 xv = *(const float2*)(x + (size_t)node * 128 + lane * 2);
        float2 o;
        o.x = fmaf(ax, rdeg, xv.x);
        o.y = fmaf(ay, rdeg, xv.y);
        *(float2*)(Us + r * 128 + lane * 2) = o;
    }
    __syncthreads();

    int jq = t & 63;   // column quad: cols 4*jq..4*jq+3
    int rq = t >> 6;   // row quad group: rows 4*rq..4*rq+3
    float acc[4][4] = {};
    const float4* Wv = (const float4*)W;   // W[128][256]

    for (int k4 = 0; k4 < 32; ++k4) {
        float4 wv[4];
        #pragma unroll
        for (int i = 0; i < 4; ++i) wv[i] = Wv[(size_t)(k4 * 4 + i) * 64 + jq];
        #pragma unroll
        for (int r = 0; r < 4; ++r) {
            float4 uv = *(const float4*)(Us + (rq * 4 + r) * 128 + k4 * 4);
            float uk0 = uv.x, uk1 = uv.y, uk2 = uv.z, uk3 = uv.w;
            acc[r][0] = fmaf(uk0, wv[0].x, acc[r][0]);
            acc[r][1] = fmaf(uk0, wv[0].y, acc[r][1]);
            acc[r][2] = fmaf(uk0, wv[0].z, acc[r][2]);
            acc[r][3] = fmaf(uk0, wv[0].w, acc[r][3]);
            acc[r][0] = fmaf(uk1, wv[1].x, acc[r][0]);
            acc[r][1] = fmaf(uk1, wv[1].y, acc[r][1]);
            acc[r][2] = fmaf(uk1, wv[1].z, acc[r][2]);
            acc[r][3] = fmaf(uk1, wv[1].w, acc[r][3]);
            acc[r][0] = fmaf(uk2, wv[2].x, acc[r][0]);
            acc[r][1] = fmaf(uk2, wv[2].y, acc[r][1]);
            acc[r][2] = fmaf(uk2, wv[2].z, acc[r][2]);
            acc[r][3] = fmaf(uk2, wv[2].w, acc[r][3]);
            acc[r][0] = fmaf(uk3, wv[3].x, acc[r][0]);
            acc[r][1] = fmaf(uk3, wv[3].y, acc[r][1]);
            acc[r][2] = fmaf(uk3, wv[3].z, acc[r][2]);
            acc[r][3] = fmaf(uk3, wv[3].w, acc[r][3]);
        }
    }

    #pragma unroll
    for (int r = 0; r < 4; ++r) {
        float4 o;
        o.x = fmaxf(acc[r][0], 0.0f);
        o.y = fmaxf(acc[r][1], 0.0f);
        o.z = fmaxf(acc[r][2], 0.0f);
        o.w = fmaxf(acc[r][3], 0.0f);
        *(float4*)(Z + (size_t)(sbase + rq * 4 + r) * 256 + jq * 4) = o;
    }
}

// ------------------------------------------------------------------- sinkhorn
// 128-thread blocks (2 waves), TWO independent OT tasks per wave for ILP
// (chain-latency-bound kernel: while task0 waits on its LDS round-trip,
// task1 issues). K matrices updated MULTIPLICATIVELY at re-absorption
// (K *= exp2(delta-potential)) so no C registers are held.
//  blocks [0,2048):    diagonal — wave = {(a,a),(b,b)} x 2 pairs.
//  blocks [2048,4096): off-diagonal OT(a,b) x 2 pairs.
__global__ __launch_bounds__(128, 4) void k_sinkhorn(
        const float* __restrict__ Z, float* __restrict__ dist) {
    __shared__ __align__(16) float smem[2][1280];   // 10240 B

    int w = threadIdx.x >> 6;
    int lane = threadIdx.x & 63;
    float* S = &smem[w][0];
    const float CSCALE = -INV_EPS * LOG2E_F;
    const float CBIAS  = -LN32_F * LOG2E_F;

    if (blockIdx.x < 2048) {
        // ============ diagonal path: 2 pairs/wave = 4 OTs ============
        int h = lane >> 5, i = lane & 31;
        int q = (i >> 4) & 1;
        int ip = i ^ 16;
        int Pb = blockIdx.x * 4 + w * 2;          // pairs Pb, Pb+1

        // LDS: sP[tk] = S + tk*512 (+h*256); sw[tk] = S+1024+tk*64; sd=S+1152+tk*64
        f2 KA[2][8], KB[2][8];
        float pp[2] = {0.0f, 0.0f}, E[2] = {1.0f, 1.0f};
        float wcur[2] = {1.0f, 1.0f}, wprev[2] = {1.0f, 1.0f};

        #pragma unroll
        for (int tk = 0; tk < 2; ++tk) {
            int P = Pb + tk;
            int src = h ? (N_PAIRS + P) : P;
            float* sP = S + tk * 512 + h * 256;
            const float4* zp = (const float4*)(Z + (size_t)src * 256);
            *(float4*)(&sP[i * 8])     = zp[i * 2];
            *(float4*)(&sP[i * 8 + 4]) = zp[i * 2 + 1];
            // initial K = exp2(C2) directly (pp=0); no C registers kept
            const f2* xp = (const f2*)(&sP[i * 8]);
            f2 x0 = xp[0], x1 = xp[1], x2 = xp[2], x3 = xp[3];
            const f2* bp = (const f2*)(&sP[ip * 8]);
            f2 b0 = bp[0], b1 = bp[1], b2 = bp[2], b3 = bp[3];
            #pragma unroll
            for (int t = 0; t < 16; ++t) {
                int j = q * 16 + t;
                const f2* yp = (const f2*)(&sP[j * 8]);
                f2 y0 = yp[0], y1 = yp[1], y2 = yp[2], y3 = yp[3];
                f2 d, s2;
                d = x0 - y0; s2 = d * d;
                d = x1 - y1; s2 = __builtin_elementwise_fma(d, d, s2);
                d = x2 - y2; s2 = __builtin_elementwise_fma(d, d, s2);
                d = x3 - y3; s2 = __builtin_elementwise_fma(d, d, s2);
                float d2 = s2.x + s2.y + 1e-12f;
                KA[tk][t >> 1][t & 1] = __builtin_amdgcn_exp2f(
                    fmaf(__builtin_amdgcn_sqrtf(d2), CSCALE, CBIAS));
                d = b0 - y0; s2 = d * d;
                d = b1 - y1; s2 = __builtin_elementwise_fma(d, d, s2);
                d = b2 - y2; s2 = __builtin_elementwise_fma(d, d, s2);
                d = b3 - y3; s2 = __builtin_elementwise_fma(d, d, s2);
                float e2 = s2.x + s2.y + 1e-12f;
                KB[tk][t >> 1][t & 1] = __builtin_amdgcn_exp2f(
                    fmaf(__builtin_amdgcn_sqrtf(e2), CSCALE, CBIAS));
            }
            (S + 1024 + tk * 64)[lane] = 1.0f;    // w init
        }

        const int blens[9] = {4, 12, 12, 12, 12, 12, 12, 12, 12};  // 100 T-steps
        #pragma unroll 1
        for (int blk = 0; blk < 9; ++blk) {
            int L = blens[blk];
            #pragma unroll 1
            for (int s = 0; s < L; ++s) {
                #pragma unroll
                for (int tk = 0; tk < 2; ++tk) {
                    float* swv = S + 1024 + tk * 64;
                    const float4* wp = (const float4*)(&swv[h * 32 + q * 16]);
                    float4 A0 = wp[0], A1 = wp[1], A2 = wp[2], A3 = wp[3];
                    f2 aA0 = KA[tk][0] * f2{A0.x, A0.y};
                    f2 aA1 = KA[tk][1] * f2{A0.z, A0.w};
                    f2 aB0 = KB[tk][0] * f2{A0.x, A0.y};
                    f2 aB1 = KB[tk][1] * f2{A0.z, A0.w};
                    aA0 = __builtin_elementwise_fma(KA[tk][2], f2{A1.x, A1.y}, aA0);
                    aA1 = __builtin_elementwise_fma(KA[tk][3], f2{A1.z, A1.w}, aA1);
                    aB0 = __builtin_elementwise_fma(KB[tk][2], f2{A1.x, A1.y}, aB0);
                    aB1 = __builtin_elementwise_fma(KB[tk][3], f2{A1.z, A1.w}, aB1);
                    aA0 = __builtin_elementwise_fma(KA[tk][4], f2{A2.x, A2.y}, aA0);
                    aA1 = __builtin_elementwise_fma(KA[tk][5], f2{A2.z, A2.w}, aA1);
                    aB0 = __builtin_elementwise_fma(KB[tk][4], f2{A2.x, A2.y}, aB0);
                    aB1 = __builtin_elementwise_fma(KB[tk][5], f2{A2.z, A2.w}, aB1);
                    aA0 = __builtin_elementwise_fma(KA[tk][6], f2{A3.x, A3.y}, aA0);
                    aA1 = __builtin_elementwise_fma(KA[tk][7], f2{A3.z, A3.w}, aA1);
                    aB0 = __builtin_elementwise_fma(KB[tk][6], f2{A3.x, A3.y}, aB0);
                    aB1 = __builtin_elementwise_fma(KB[tk][7], f2{A3.z, A3.w}, aB1);
                    f2 aa = aA0 + aA1;
                    f2 bb = aB0 + aB1;
                    float pa = aa.x + aa.y;
                    float pb = bb.x + bb.y;
                    float other = __shfl_xor(pb, 16);
                    float Sv = pa + other;
                    wprev[tk] = wcur[tk];
                    wcur[tk] = __builtin_amdgcn_rcpf(Sv) * E[tk];
                    swv[h * 32 + i] = wcur[tk];
                }
            }
            if (blk < 8) {
                #pragma unroll
                for (int tk = 0; tk < 2; ++tk) {
                    float* swv = S + 1024 + tk * 64;
                    float* sdp = S + 1152 + tk * 64;
                    float d = __builtin_amdgcn_logf(wcur[tk]);
                    pp[tk] += d;
                    sdp[h * 32 + i] = d;
                    const float4* dv = (const float4*)(&sdp[h * 32 + q * 16]);
                    float4 D0 = dv[0], D1 = dv[1], D2 = dv[2], D3 = dv[3];
                    float ex[16];
                    ex[0] = __builtin_amdgcn_exp2f(D0.x);
                    ex[1] = __builtin_amdgcn_exp2f(D0.y);
                    ex[2] = __builtin_amdgcn_exp2f(D0.z);
                    ex[3] = __builtin_amdgcn_exp2f(D0.w);
                    ex[4] = __builtin_amdgcn_exp2f(D1.x);
                    ex[5] = __builtin_amdgcn_exp2f(D1.y);
                    ex[6] = __builtin_amdgcn_exp2f(D1.z);
                    ex[7] = __builtin_amdgcn_exp2f(D1.w);
                    ex[8] = __builtin_amdgcn_exp2f(D2.x);
                    ex[9] = __builtin_amdgcn_exp2f(D2.y);
                    ex[10] = __builtin_amdgcn_exp2f(D2.z);
                    ex[11] = __builtin_amdgcn_exp2f(D2.w);
                    ex[12] = __builtin_amdgcn_exp2f(D3.x);
                    ex[13] = __builtin_amdgcn_exp2f(D3.y);
                    ex[14] = __builtin_amdgcn_exp2f(D3.z);
                    ex[15] = __builtin_amdgcn_exp2f(D3.w);
                    #pragma unroll
                    for (int t2 = 0; t2 < 8; ++t2) {
                        f2 ee = f2{ex[2 * t2], ex[2 * t2 + 1]};
                        KA[tk][t2] *= ee;
                        KB[tk][t2] *= ee;
                    }
                    E[tk] = __builtin_amdgcn_exp2f(-pp[tk]);
                    wcur[tk] = 1.0f;
                    swv[lane] = 1.0f;
                }
            }
        }

        #pragma unroll
        for (int tk = 0; tk < 2; ++tk) {
            float zsum = 2.0f * pp[tk] + __builtin_amdgcn_logf(wprev[tk])
                       + __builtin_amdgcn_logf(wcur[tk]);
            #pragma unroll
            for (int off = 16; off > 0; off >>= 1) zsum += __shfl_xor(zsum, off);
            if (i == 0) {
                float cost = zsum * (EPS_F * LN2_F / 32.0f);
                unsafeAtomicAdd(&dist[Pb + tk], -0.5f * cost);
            }
        }
    } else {
        // ============ off-diagonal path: 2 pairs/wave ============
        int jh = lane >> 5;                    // row layout: i=lane&31, half jh
        int ih = lane >> 5;                    // col layout: j=lane&31, half ih
        int i_r = lane & 31;
        int Bb = (blockIdx.x - 2048) * 4 + w * 2;   // pairs Bb, Bb+1

        // LDS: sX[tk]=S+tk*512, sY=+256; sf=S+1024+tk*128, sg=+32, su=+64, sv=+96
        f2 KR[2][8], KC[2][8];
        float ftA[2], gtA[2];
        float ureg[2] = {1.0f, 1.0f}, vreg[2] = {1.0f, 1.0f};

        // -------- setup + phase A (2 log-domain iters), sequential per task
        #pragma unroll 1
        for (int tk = 0; tk < 2; ++tk) {
            int b = Bb + tk;
            float* sX = S + tk * 512;
            float* sY = sX + 256;
            float* sf = S + 1024 + tk * 128;
            float* sg = sf + 32;
            float* sv = sf + 96;
            *(float4*)(&sX[lane * 4]) = ((const float4*)(Z + (size_t)b * 256))[lane];
            *(float4*)(&sY[lane * 4]) = ((const float4*)(Z + (size_t)(N_PAIRS + b) * 256))[lane];
            sg[i_r] = 0.0f;

            f2 CrowV[8], CcolV[8];
            {
                const f2* xp = (const f2*)(&sX[i_r * 8]);
                f2 x0 = xp[0], x1 = xp[1], x2 = xp[2], x3 = xp[3];
                #pragma unroll
                for (int t = 0; t < 16; ++t) {
                    int j = jh * 16 + t;
                    const f2* yp = (const f2*)(&sY[j * 8]);
                    f2 d, s2;
                    d = x0 - yp[0]; s2 = d * d;
                    d = x1 - yp[1]; s2 = __builtin_elementwise_fma(d, d, s2);
                    d = x2 - yp[2]; s2 = __builtin_elementwise_fma(d, d, s2);
                    d = x3 - yp[3]; s2 = __builtin_elementwise_fma(d, d, s2);
                    float d2 = s2.x + s2.y + 1e-12f;
                    CrowV[t >> 1][t & 1] = fmaf(__builtin_amdgcn_sqrtf(d2), CSCALE, CBIAS);
                }
                const f2* yp = (const f2*)(&sY[i_r * 8]);
                f2 y0 = yp[0], y1 = yp[1], y2 = yp[2], y3 = yp[3];
                #pragma unroll
                for (int t = 0; t < 16; ++t) {
                    int i = ih * 16 + t;
                    const f2* qp = (const f2*)(&sX[i * 8]);
                    f2 d, s2;
                    d = qp[0] - y0; s2 = d * d;
                    d = qp[1] - y1; s2 = __builtin_elementwise_fma(d, d, s2);
                    d = qp[2] - y2; s2 = __builtin_elementwise_fma(d, d, s2);
                    d = qp[3] - y3; s2 = __builtin_elementwise_fma(d, d, s2);
                    float d2 = s2.x + s2.y + 1e-12f;
                    CcolV[t >> 1][t & 1] = fmaf(__builtin_amdgcn_sqrtf(d2), CSCALE, CBIAS);
                }
            }

            float ft = 0.0f, gt = 0.0f;
            #pragma unroll 1
            for (int it = 0; it < 2; ++it) {
                {
                    const float4* gp = (const float4*)(&sg[jh * 16]);
                    float4 G0 = gp[0], G1 = gp[1], G2 = gp[2], G3 = gp[3];
                    f2 gv[8] = {f2{G0.x, G0.y}, f2{G0.z, G0.w}, f2{G1.x, G1.y}, f2{G1.z, G1.w},
                                f2{G2.x, G2.y}, f2{G2.z, G2.w}, f2{G3.x, G3.y}, f2{G3.z, G3.w}};
                    f2 val[8], m2 = f2{-1e30f, -1e30f};
                    #pragma unroll
                    for (int t2 = 0; t2 < 8; ++t2) {
                        val[t2] = gv[t2] + CrowV[t2];
                        m2 = __builtin_elementwise_max(m2, val[t2]);
                    }
                    float m = fmaxf(m2.x, m2.y);
                    m = fmaxf(m, __shfl_xor(m, 32));
                    f2 mm = f2{m, m};
                    float s0 = 0.0f, s1 = 0.0f;
                    #pragma unroll
                    for (int t2 = 0; t2 < 8; ++t2) {
                        f2 e = val[t2] - mm;
                        s0 += __builtin_amdgcn_exp2f(e.x);
                        s1 += __builtin_amdgcn_exp2f(e.y);
                    }
                    float s = s0 + s1;
                    s += __shfl_xor(s, 32);
                    ft = -(m + __builtin_amdgcn_logf(s));
                }
                sf[i_r] = ft;
                {
                    const float4* fp = (const float4*)(&sf[ih * 16]);
                    float4 F0 = fp[0], F1 = fp[1], F2 = fp[2], F3 = fp[3];
                    f2 fv[8] = {f2{F0.x, F0.y}, f2{F0.z, F0.w}, f2{F1.x, F1.y}, f2{F1.z, F1.w},
                                f2{F2.x, F2.y}, f2{F2.z, F2.w}, f2{F3.x, F3.y}, f2{F3.z, F3.w}};
                    f2 val[8], m2 = f2{-1e30f, -1e30f};
                    #pragma unroll
                    for (int t2 = 0; t2 < 8; ++t2) {
                        val[t2] = fv[t2] + CcolV[t2];
                        m2 = __builtin_elementwise_max(m2, val[t2]);
                    }
                    float m = fmaxf(m2.x, m2.y);
                    m = fmaxf(m, __shfl_xor(m, 32));
                    f2 mm = f2{m, m};
                    float s0 = 0.0f, s1 = 0.0f;
                    #pragma unroll
                    for (int t2 = 0; t2 < 8; ++t2) {
                        f2 e = val[t2] - mm;
                        s0 += __builtin_amdgcn_exp2f(e.x);
                        s1 += __builtin_amdgcn_exp2f(e.y);
                    }
                    float s = s0 + s1;
                    s += __shfl_xor(s, 32);
                    gt = -(m + __builtin_amdgcn_logf(s));
                }
                sg[i_r] = gt;
            }

            // build K from C (C dies after this)
            {
                const float4* gp = (const float4*)(&sg[jh * 16]);
                float4 G0 = gp[0], G1 = gp[1], G2 = gp[2], G3 = gp[3];
                f2 gv[8] = {f2{G0.x, G0.y}, f2{G0.z, G0.w}, f2{G1.x, G1.y}, f2{G1.z, G1.w},
                            f2{G2.x, G2.y}, f2{G2.z, G2.w}, f2{G3.x, G3.y}, f2{G3.z, G3.w}};
                f2 ftv = f2{ft, ft};
                #pragma unroll
                for (int t2 = 0; t2 < 8; ++t2) {
                    f2 a = (gv[t2] + CrowV[t2]) + ftv;
                    KR[tk][t2].x = __builtin_amdgcn_exp2f(a.x);
                    KR[tk][t2].y = __builtin_amdgcn_exp2f(a.y);
                }
                const float4* fp = (const float4*)(&sf[ih * 16]);
                float4 F0 = fp[0], F1 = fp[1], F2 = fp[2], F3 = fp[3];
                f2 fv[8] = {f2{F0.x, F0.y}, f2{F0.z, F0.w}, f2{F1.x, F1.y}, f2{F1.z, F1.w},
                            f2{F2.x, F2.y}, f2{F2.z, F2.w}, f2{F3.x, F3.y}, f2{F3.z, F3.w}};
                f2 gtv = f2{gt, gt};
                #pragma unroll
                for (int t2 = 0; t2 < 8; ++t2) {
                    f2 a = (fv[t2] + CcolV[t2]) + gtv;
                    KC[tk][t2].x = __builtin_amdgcn_exp2f(a.x);
                    KC[tk][t2].y = __builtin_amdgcn_exp2f(a.y);
                }
            }
            sv[i_r] = 1.0f;
            ftA[tk] = ft;
            gtA[tk] = gt;
        }

        // -------- phase B: interleaved absorbed exp-domain
        const int blens[5] = {6, 6, 12, 12, 12};   // 48 exp iters total
        #pragma unroll 1
        for (int blk = 0; blk < 5; ++blk) {
            int L = blens[blk];
            #pragma unroll 1
            for (int s6 = 0; s6 < L; ++s6) {
                #pragma unroll
                for (int tk = 0; tk < 2; ++tk) {
                    float* su = S + 1024 + tk * 128 + 64;
                    float* sv = su + 32;
                    const float4* vp = (const float4*)(&sv[jh * 16]);
                    float4 A0 = vp[0], A1 = vp[1], A2 = vp[2], A3 = vp[3];
                    f2 acc0 = KR[tk][0] * f2{A0.x, A0.y};
                    f2 acc1 = KR[tk][1] * f2{A0.z, A0.w};
                    acc0 = __builtin_elementwise_fma(KR[tk][2], f2{A1.x, A1.y}, acc0);
                    acc1 = __builtin_elementwise_fma(KR[tk][3], f2{A1.z, A1.w}, acc1);
                    acc0 = __builtin_elementwise_fma(KR[tk][4], f2{A2.x, A2.y}, acc0);
                    acc1 = __builtin_elementwise_fma(KR[tk][5], f2{A2.z, A2.w}, acc1);
                    acc0 = __builtin_elementwise_fma(KR[tk][6], f2{A3.x, A3.y}, acc0);
                    acc1 = __builtin_elementwise_fma(KR[tk][7], f2{A3.z, A3.w}, acc1);
                    f2 a = acc0 + acc1;
                    float Sv = a.x + a.y;
                    Sv += __shfl_xor(Sv, 32);
                    ureg[tk] = __builtin_amdgcn_rcpf(Sv);
                    su[i_r] = ureg[tk];
                }
                #pragma unroll
                for (int tk = 0; tk < 2; ++tk) {
                    float* su = S + 1024 + tk * 128 + 64;
                    float* sv = su + 32;
                    const float4* up = (const float4*)(&su[ih * 16]);
                    float4 A0 = up[0], A1 = up[1], A2 = up[2], A3 = up[3];
                    f2 acc0 = KC[tk][0] * f2{A0.x, A0.y};
                    f2 acc1 = KC[tk][1] * f2{A0.z, A0.w};
                    acc0 = __builtin_elementwise_fma(KC[tk][2], f2{A1.x, A1.y}, acc0);
                    acc1 = __builtin_elementwise_fma(KC[tk][3], f2{A1.z, A1.w}, acc1);
                    acc0 = __builtin_elementwise_fma(KC[tk][4], f2{A2.x, A2.y}, acc0);
                    acc1 = __builtin_elementwise_fma(KC[tk][5], f2{A2.z, A2.w}, acc1);
                    acc0 = __builtin_elementwise_fma(KC[tk][6], f2{A3.x, A3.y}, acc0);
                    acc1 = __builtin_elementwise_fma(KC[tk][7], f2{A3.z, A3.w}, acc1);
                    f2 a = acc0 + acc1;
                    float Tv = a.x + a.y;
                    Tv += __shfl_xor(Tv, 32);
                    vreg[tk] = __builtin_amdgcn_rcpf(Tv);
                    sv[i_r] = vreg[tk];
                }
            }
            if (blk < 4) {
                #pragma unroll
                for (int tk = 0; tk < 2; ++tk) {
                    float* sf = S + 1024 + tk * 128;
                    float* sg = sf + 32;
                    float* sv = sf + 96;
                    float df = __builtin_amdgcn_logf(ureg[tk]);
                    float dg = __builtin_amdgcn_logf(vreg[tk]);
                    ftA[tk] += df;
                    gtA[tk] += dg;
                    sf[i_r] = df;
                    sg[i_r] = dg;
                    // KR[i][j-set] *= exp2(df_i + dg_j)
                    const float4* dgv = (const float4*)(&sg[jh * 16]);
                    float4 D0 = dgv[0], D1 = dgv[1], D2 = dgv[2], D3 = dgv[3];
                    float ex[16];
                    ex[0] = __builtin_amdgcn_exp2f(df + D0.x);
                    ex[1] = __builtin_amdgcn_exp2f(df + D0.y);
                    ex[2] = __builtin_amdgcn_exp2f(df + D0.z);
                    ex[3] = __builtin_amdgcn_exp2f(df + D0.w);
                    ex[4] = __builtin_amdgcn_exp2f(df + D1.x);
                    ex[5] = __builtin_amdgcn_exp2f(df + D1.y);
                    ex[6] = __builtin_amdgcn_exp2f(df + D1.z);
                    ex[7] = __builtin_amdgcn_exp2f(df + D1.w);
                    ex[8] = __builtin_amdgcn_exp2f(df + D2.x);
                    ex[9] = __builtin_amdgcn_exp2f(df + D2.y);
                    ex[10] = __builtin_amdgcn_exp2f(df + D2.z);
                    ex[11] = __builtin_amdgcn_exp2f(df + D2.w);
                    ex[12] = __builtin_amdgcn_exp2f(df + D3.x);
                    ex[13] = __builtin_amdgcn_exp2f(df + D3.y);
                    ex[14] = __builtin_amdgcn_exp2f(df + D3.z);
                    ex[15] = __builtin_amdgcn_exp2f(df + D3.w);
                    #pragma unroll
                    for (int t2 = 0; t2 < 8; ++t2)
                        KR[tk][t2] *= f2{ex[2 * t2], ex[2 * t2 + 1]};
                    // KC[j][i-set] *= exp2(dg_j + df_i)
                    const float4* dfv = (const float4*)(&sf[ih * 16]);
                    float4 E0 = dfv[0], E1 = dfv[1], E2 = dfv[2], E3 = dfv[3];
                    ex[0] = __builtin_amdgcn_exp2f(dg + E0.x);
                    ex[1] = __builtin_amdgcn_exp2f(dg + E0.y);
                    ex[2] = __builtin_amdgcn_exp2f(dg + E0.z);
                    ex[3] = __builtin_amdgcn_exp2f(dg + E0.w);
                    ex[4] = __builtin_amdgcn_exp2f(dg + E1.x);
                    ex[5] = __builtin_amdgcn_exp2f(dg + E1.y);
                    ex[6] = __builtin_amdgcn_exp2f(dg + E1.z);
                    ex[7] = __builtin_amdgcn_exp2f(dg + E1.w);
                    ex[8] = __builtin_amdgcn_exp2f(dg + E2.x);
                    ex[9] = __builtin_amdgcn_exp2f(dg + E2.y);
                    ex[10] = __builtin_amdgcn_exp2f(dg + E2.z);
                    ex[11] = __builtin_amdgcn_exp2f(dg + E2.w);
                    ex[12] = __builtin_amdgcn_exp2f(dg + E3.x);
                    ex[13] = __builtin_amdgcn_exp2f(dg + E3.y);
                    ex[14] = __builtin_amdgcn_exp2f(dg + E3.z);
                    ex[15] = __builtin_amdgcn_exp2f(dg + E3.w);
                    #pragma unroll
                    for (int t2 = 0; t2 < 8; ++t2)
                        KC[tk][t2] *= f2{ex[2 * t2], ex[2 * t2 + 1]};
                    sv[i_r] = 1.0f;
                    ureg[tk] = 1.0f;
                    vreg[tk] = 1.0f;
                }
            }
        }

        #pragma unroll
        for (int tk = 0; tk < 2; ++tk) {
            float ft = ftA[tk] + __builtin_amdgcn_logf(ureg[tk]);
            float gt = gtA[tk] + __builtin_amdgcn_logf(vreg[tk]);
            float v = ft + gt;
            #pragma unroll
            for (int off = 32; off > 0; off >>= 1) v += __shfl_xor(v, off);
            if (lane == 0) {
                float cost = v * (EPS_F * LN2_F / 64.0f);
                unsafeAtomicAdd(&dist[Bb + tk], cost);
            }
        }
    }
}

// ------------------------------------------------------------------ finalize
__global__ void k_finalize(const float* __restrict__ dist,
                           const float* __restrict__ gd, float* __restrict__ out) {
    __shared__ float red[256];
    float s = 0.0f;
    for (int i = threadIdx.x; i < N_PAIRS; i += 256) {
        float g = gd[i];
        s += fabsf(dist[i] - g) / g;
    }
    red[threadIdx.x] = s;
    __syncthreads();
    for (int o = 128; o > 0; o >>= 1) {
        if (threadIdx.x < o) red[threadIdx.x] += red[threadIdx.x + o];
        __syncthreads();
    }
    if (threadIdx.x == 0) out[0] = red[0] * (1.0f / N_PAIRS);
}

// -------------------------------------------------------------------- launch
extern "C" void kernel_launch(void* const* d_in, const int* in_sizes, int n_in,
                              void* d_out, int out_size, void* d_ws, size_t ws_size,
                              hipStream_t stream) {
    const float* x    = (const float*)d_in[0];   // [50000,128]
    const float* W    = (const float*)d_in[1];   // [128,256]
    const int*   eidx = (const int*)d_in[2];     // [2,800000]
    const int*   pair = (const int*)d_in[3];     // [2,8192] flat = 16384 slots
    const float* gd   = (const float*)d_in[4];   // [8192]

    char* ws = (char*)d_ws;
    size_t off = 0;
    int*   cnt    = (int*)  (ws + off); off += (size_t)N_NODES * 4;
    int*   flags  = (int*)  (ws + off); off += (size_t)N_NODES * 4;
    float* dist   = (float*)(ws + off); off += (size_t)N_PAIRS * 4;
    size_t zero_bytes = off;                     // cnt+flags+dist contiguous
    int*   bucket = (int*)  (ws + off); off += (size_t)N_NODES * CAP * 4; // 12.8 MB
    float* Z      = (float*)(ws + off); off += (size_t)N_SLOTS * 256 * 4; // 16.8 MB

    hipMemsetAsync(d_ws, 0, zero_bytes, stream);
    k_mark    <<<(N_SLOTS + 255) / 256, 256, 0, stream>>>(pair, flags);
    k_scatter <<<N_EDGES / 256, 256, 0, stream>>>(eidx, flags, cnt, bucket);
    k_gemm    <<<N_SLOTS / 16, 256, 0, stream>>>(pair, x, cnt, bucket, W, Z);
    k_sinkhorn<<<4096, 128, 0, stream>>>(Z, dist);
    k_finalize<<<1, 256, 0, stream>>>(dist, gd, (float*)d_out);
}

// Round 10
// 243.948 us; speedup vs baseline: 1.0788x; 1.0788x over previous
//
#include <hip/hip_runtime.h>

#define N_NODES 50000
#define N_EDGES 800000
#define N_PAIRS 8192
#define N_SLOTS (2 * N_PAIRS)
#define CAP     64          // per-node bucket capacity; P(deg>63)~5e-19

// Sinkhorn constants (log2 domain):
//   C2 = -(C/eps + ln32)*log2e ; potentials kept in /(eps*ln2) units
#define INV_EPS   20.0f
#define LOG2E_F   1.4426950408889634f
#define LN2_F     0.6931471805599453f
#define LN32_F    3.4657359027997265f
#define EPS_F     0.05f

typedef float f2 __attribute__((ext_vector_type(2)));

// ---------------------------------------------------------------- mark needed
__global__ void k_mark(const int* __restrict__ pairs, int* __restrict__ flags) {
    int t = blockIdx.x * 256 + threadIdx.x;
    if (t < N_SLOTS) flags[pairs[t]] = 1;
}

// ---------------------------------------- scatter into fixed-cap buckets
__global__ __launch_bounds__(256) void k_scatter(
        const int* __restrict__ eidx, const int* __restrict__ flags,
        int* __restrict__ cnt, int* __restrict__ bucket) {
    int t = blockIdx.x * 256 + threadIdx.x;   // exact grid: 800000/256
    int dst = eidx[N_EDGES + t];
    if (!flags[dst]) return;
    int pos = atomicAdd(&cnt[dst], 1);
    if (pos < CAP) bucket[dst * CAP + pos] = eidx[t];
}

// ------------------------------------ fused gather + GEMM + relu
__global__ __launch_bounds__(256) void k_gemm(
        const int* __restrict__ pairs, const float* __restrict__ x,
        const int* __restrict__ cnt, const int* __restrict__ bucket,
        const float* __restrict__ W, float* __restrict__ Z) {
    __shared__ __align__(16) float Us[16 * 128];
    int sbase = blockIdx.x * 16;
    int t = threadIdx.x;
    int wave = t >> 6, lane = t & 63;

    #pragma unroll
    for (int rr = 0; rr < 4; ++rr) {
        int r = wave * 4 + rr;
        int node = pairs[sbase + r];
        int n = cnt[node];
        int m = (n < CAP) ? n : CAP;
        const int* bk = bucket + node * CAP;
        float ax = 0.0f, ay = 0.0f;
        int k = 0;
        for (; k + 4 <= m; k += 4) {
            int s0 = bk[k], s1 = bk[k + 1], s2 = bk[k + 2], s3 = bk[k + 3];
            float2 v0 = *(const float2*)(x + (size_t)s0 * 128 + lane * 2);
            float2 v1 = *(const float2*)(x + (size_t)s1 * 128 + lane * 2);
            float2 v2 = *(const float2*)(x + (size_t)s2 * 128 + lane * 2);
            float2 v3 = *(const float2*)(x + (size_t)s3 * 128 + lane * 2);
            ax += (v0.x + v1.x) + (v2.x + v3.x);
            ay += (v0.y + v1.y) + (v2.y + v3.y);
        }
        for (; k < m; ++k) {
            int s0 = bk[k];
            float2 v0 = *(const float2*)(x + (size_t)s0 * 128 + lane * 2);
            ax += v0.x;
            ay += v0.y;
        }
        float rdeg = 1.0f / fmaxf((float)n, 1.0f);
        float2 xv = *(const float2*)(x + (size_t)node * 128 + lane * 2);
        float2 o;
        o.x = fmaf(ax, rdeg, xv.x);
        o.y = fmaf(ay, rdeg, xv.y);
        *(float2*)(Us + r * 128 + lane * 2) = o;
    }
    __syncthreads();

    int jq = t & 63;   // column quad: cols 4*jq..4*jq+3
    int rq = t >> 6;   // row quad group: rows 4*rq..4*rq+3
    float acc[4][4] = {};
    const float4* Wv = (const float4*)W;   // W[128][256]

    for (int k4 = 0; k4 < 32; ++k4) {
        float4 wv[4];
        #pragma unroll
        for (int i = 0; i < 4; ++i) wv[i] = Wv[(size_t)(k4 * 4 + i) * 64 + jq];
        #pragma unroll
        for (int r = 0; r < 4; ++r) {
            float4 uv = *(const float4*)(Us + (rq * 4 + r) * 128 + k4 * 4);
            float uk0 = uv.x, uk1 = uv.y, uk2 = uv.z, uk3 = uv.w;
            acc[r][0] = fmaf(uk0, wv[0].x, acc[r][0]);
            acc[r][1] = fmaf(uk0, wv[0].y, acc[r][1]);
            acc[r][2] = fmaf(uk0, wv[0].z, acc[r][2]);
            acc[r][3] = fmaf(uk0, wv[0].w, acc[r][3]);
            acc[r][0] = fmaf(uk1, wv[1].x, acc[r][0]);
            acc[r][1] = fmaf(uk1, wv[1].y, acc[r][1]);
            acc[r][2] = fmaf(uk1, wv[1].z, acc[r][2]);
            acc[r][3] = fmaf(uk1, wv[1].w, acc[r][3]);
            acc[r][0] = fmaf(uk2, wv[2].x, acc[r][0]);
            acc[r][1] = fmaf(uk2, wv[2].y, acc[r][1]);
            acc[r][2] = fmaf(uk2, wv[2].z, acc[r][2]);
            acc[r][3] = fmaf(uk2, wv[2].w, acc[r][3]);
            acc[r][0] = fmaf(uk3, wv[3].x, acc[r][0]);
            acc[r][1] = fmaf(uk3, wv[3].y, acc[r][1]);
            acc[r][2] = fmaf(uk3, wv[3].z, acc[r][2]);
            acc[r][3] = fmaf(uk3, wv[3].w, acc[r][3]);
        }
    }

    #pragma unroll
    for (int r = 0; r < 4; ++r) {
        float4 o;
        o.x = fmaxf(acc[r][0], 0.0f);
        o.y = fmaxf(acc[r][1], 0.0f);
        o.z = fmaxf(acc[r][2], 0.0f);
        o.w = fmaxf(acc[r][3], 0.0f);
        *(float4*)(Z + (size_t)(sbase + rq * 4 + r) * 256 + jq * 4) = o;
    }
}

// ------------------------------------------------------------------- sinkhorn
// 128-thread blocks (2 waves), no __syncthreads anywhere.
//  blocks [0,4096):    diagonal — one wave per pair: (a,a) in half 0 and
//                      (b,b) in half 1; pair-split dot + one shfl_xor(16).
//  blocks [4096,6144): off-diagonal — HALF-WAVE per pair (2 pairs/wave):
//                      lane = full row (f-step) / full col (g-step), full
//                      32-wide dot in registers, ZERO cross-lane shuffles
//                      in the iteration; K row+col copies updated
//                      multiplicatively at re-absorption.
__global__ __launch_bounds__(128) void k_sinkhorn(
        const float* __restrict__ Z, float* __restrict__ dist) {
    __shared__ __align__(16) float smem[2][1280];   // 10240 B

    int w = threadIdx.x >> 6;
    int lane = threadIdx.x & 63;
    float* S = &smem[w][0];
    const float CSCALE = -INV_EPS * LOG2E_F;
    const float CBIAS  = -LN32_F * LOG2E_F;

    if (blockIdx.x < 4096) {
        // ============ diagonal path: OT(a,a) & OT(b,b), 1 pair/wave ========
        int h = lane >> 5, i = lane & 31;
        int q = (i >> 4) & 1;                 // k-half this lane reads
        int ip = i ^ 16;                      // partner row
        int P = blockIdx.x * 2 + w;           // 4096*2 = 8192 pairs
        int src = h ? (N_PAIRS + P) : P;

        float* sP  = S + h * 256;             // own half's cloud
        float* swv = S + 512;                 // w vector [h*32 + j]
        float* spv = S + 576;                 // p vector at absorb

        {
            const float4* zp = (const float4*)(Z + (size_t)src * 256);
            *(float4*)(&sP[i * 8])     = zp[i * 2];
            *(float4*)(&sP[i * 8 + 4]) = zp[i * 2 + 1];
        }

        // CA: C[i][16q+t], CB: C[i^16][16q+t]  (t in [0,16))
        f2 CA[8], CB[8];
        {
            const f2* xp = (const f2*)(&sP[i * 8]);
            f2 x0 = xp[0], x1 = xp[1], x2 = xp[2], x3 = xp[3];
            const f2* bp = (const f2*)(&sP[ip * 8]);
            f2 b0 = bp[0], b1 = bp[1], b2 = bp[2], b3 = bp[3];
            #pragma unroll
            for (int t = 0; t < 16; ++t) {
                int j = q * 16 + t;
                const f2* yp = (const f2*)(&sP[j * 8]);
                f2 y0 = yp[0], y1 = yp[1], y2 = yp[2], y3 = yp[3];
                f2 d, s2;
                d = x0 - y0; s2 = d * d;
                d = x1 - y1; s2 = __builtin_elementwise_fma(d, d, s2);
                d = x2 - y2; s2 = __builtin_elementwise_fma(d, d, s2);
                d = x3 - y3; s2 = __builtin_elementwise_fma(d, d, s2);
                float d2 = s2.x + s2.y + 1e-12f;
                CA[t >> 1][t & 1] = fmaf(__builtin_amdgcn_sqrtf(d2), CSCALE, CBIAS);
                d = b0 - y0; s2 = d * d;
                d = b1 - y1; s2 = __builtin_elementwise_fma(d, d, s2);
                d = b2 - y2; s2 = __builtin_elementwise_fma(d, d, s2);
                d = b3 - y3; s2 = __builtin_elementwise_fma(d, d, s2);
                float e2 = s2.x + s2.y + 1e-12f;
                CB[t >> 1][t & 1] = fmaf(__builtin_amdgcn_sqrtf(e2), CSCALE, CBIAS);
            }
        }

        float pp = 0.0f, E = 1.0f, wcur = 1.0f, wprev = 1.0f;
        f2 KA[8], KB[8];
        #pragma unroll
        for (int t = 0; t < 8; ++t) {
            KA[t].x = __builtin_amdgcn_exp2f(CA[t].x);
            KA[t].y = __builtin_amdgcn_exp2f(CA[t].y);
            KB[t].x = __builtin_amdgcn_exp2f(CB[t].x);
            KB[t].y = __builtin_amdgcn_exp2f(CB[t].y);
        }
        swv[lane] = 1.0f;

        const int blens[9] = {4, 12, 12, 12, 12, 12, 12, 12, 12};  // 100 T-steps
        #pragma unroll 1
        for (int blk = 0; blk < 9; ++blk) {
            int L = blens[blk];
            #pragma unroll 2
            for (int s = 0; s < L; ++s) {
                const float4* wp = (const float4*)(&swv[h * 32 + q * 16]);
                float4 A0 = wp[0], A1 = wp[1], A2 = wp[2], A3 = wp[3];
                f2 aA0 = KA[0] * f2{A0.x, A0.y};
                f2 aA1 = KA[1] * f2{A0.z, A0.w};
                f2 aB0 = KB[0] * f2{A0.x, A0.y};
                f2 aB1 = KB[1] * f2{A0.z, A0.w};
                aA0 = __builtin_elementwise_fma(KA[2], f2{A1.x, A1.y}, aA0);
                aA1 = __builtin_elementwise_fma(KA[3], f2{A1.z, A1.w}, aA1);
                aB0 = __builtin_elementwise_fma(KB[2], f2{A1.x, A1.y}, aB0);
                aB1 = __builtin_elementwise_fma(KB[3], f2{A1.z, A1.w}, aB1);
                aA0 = __builtin_elementwise_fma(KA[4], f2{A2.x, A2.y}, aA0);
                aA1 = __builtin_elementwise_fma(KA[5], f2{A2.z, A2.w}, aA1);
                aB0 = __builtin_elementwise_fma(KB[4], f2{A2.x, A2.y}, aB0);
                aB1 = __builtin_elementwise_fma(KB[5], f2{A2.z, A2.w}, aB1);
                aA0 = __builtin_elementwise_fma(KA[6], f2{A3.x, A3.y}, aA0);
                aA1 = __builtin_elementwise_fma(KA[7], f2{A3.z, A3.w}, aA1);
                aB0 = __builtin_elementwise_fma(KB[6], f2{A3.x, A3.y}, aB0);
                aB1 = __builtin_elementwise_fma(KB[7], f2{A3.z, A3.w}, aB1);
                f2 aa = aA0 + aA1;
                f2 bb = aB0 + aB1;
                float pa = aa.x + aa.y;       // partial for row i   (k in q)
                float pb = bb.x + bb.y;       // partial for row i^16 (k in q)
                float other = __shfl_xor(pb, 16);
                float Sv = pa + other;
                wprev = wcur;
                wcur = __builtin_amdgcn_rcpf(Sv) * E;
                swv[h * 32 + i] = wcur;
            }
            if (blk < 8) {
                float d = __builtin_amdgcn_logf(wcur);
                pp += d;
                spv[h * 32 + i] = d;
                const float4* dv = (const float4*)(&spv[h * 32 + q * 16]);
                float4 D0 = dv[0], D1 = dv[1], D2 = dv[2], D3 = dv[3];
                float ex[16];
                ex[0]  = __builtin_amdgcn_exp2f(D0.x);
                ex[1]  = __builtin_amdgcn_exp2f(D0.y);
                ex[2]  = __builtin_amdgcn_exp2f(D0.z);
                ex[3]  = __builtin_amdgcn_exp2f(D0.w);
                ex[4]  = __builtin_amdgcn_exp2f(D1.x);
                ex[5]  = __builtin_amdgcn_exp2f(D1.y);
                ex[6]  = __builtin_amdgcn_exp2f(D1.z);
                ex[7]  = __builtin_amdgcn_exp2f(D1.w);
                ex[8]  = __builtin_amdgcn_exp2f(D2.x);
                ex[9]  = __builtin_amdgcn_exp2f(D2.y);
                ex[10] = __builtin_amdgcn_exp2f(D2.z);
                ex[11] = __builtin_amdgcn_exp2f(D2.w);
                ex[12] = __builtin_amdgcn_exp2f(D3.x);
                ex[13] = __builtin_amdgcn_exp2f(D3.y);
                ex[14] = __builtin_amdgcn_exp2f(D3.z);
                ex[15] = __builtin_amdgcn_exp2f(D3.w);
                #pragma unroll
                for (int t2 = 0; t2 < 8; ++t2) {
                    f2 ee = f2{ex[2 * t2], ex[2 * t2 + 1]};
                    KA[t2] *= ee;
                    KB[t2] *= ee;
                }
                E = __builtin_amdgcn_exp2f(-pp);
                wcur = 1.0f;
                swv[lane] = 1.0f;
            }
        }

        // z99 = pp + log2(wprev), z100 = pp + log2(wcur); cost = eps*ln2*sum/32
        float zsum = 2.0f * pp + __builtin_amdgcn_logf(wprev)
                   + __builtin_amdgcn_logf(wcur);
        #pragma unroll
        for (int off = 16; off > 0; off >>= 1) zsum += __shfl_xor(zsum, off);
        if (i == 0) {
            float cost = zsum * (EPS_F * LN2_F / 32.0f);
            unsafeAtomicAdd(&dist[P], -0.5f * cost);
        }
    } else {
        // ============ off-diagonal path: half-wave per pair ============
        int h = lane >> 5, l = lane & 31;
        int p = (blockIdx.x - 4096) * 4 + w * 2 + h;   // 2048*4 = 8192 pairs

        float* base = S + h * 640;
        float* sX = base;
        float* sY = base + 256;
        float* sf = base + 512;
        float* sg = base + 544;
        float* su = base + 576;
        float* sv = base + 608;

        {
            const float4* zx = (const float4*)(Z + (size_t)p * 256);
            const float4* zy = (const float4*)(Z + (size_t)(N_PAIRS + p) * 256);
            *(float4*)(&sX[l * 8])     = zx[l * 2];
            *(float4*)(&sX[l * 8 + 4]) = zx[l * 2 + 1];
            *(float4*)(&sY[l * 8])     = zy[l * 2];
            *(float4*)(&sY[l * 8 + 4]) = zy[l * 2 + 1];
        }
        sg[l] = 0.0f;

        // Crow[j] = C2[l][j]; Ccol[i] = C2[i][l]
        f2 Crow[16], Ccol[16];
        {
            const f2* xp = (const f2*)(&sX[l * 8]);
            f2 x0 = xp[0], x1 = xp[1], x2 = xp[2], x3 = xp[3];
            const f2* yp = (const f2*)(&sY[l * 8]);
            f2 y0 = yp[0], y1 = yp[1], y2 = yp[2], y3 = yp[3];
            #pragma unroll
            for (int t = 0; t < 32; ++t) {
                const f2* op = (const f2*)(&sY[t * 8]);
                f2 d, s2;
                d = x0 - op[0]; s2 = d * d;
                d = x1 - op[1]; s2 = __builtin_elementwise_fma(d, d, s2);
                d = x2 - op[2]; s2 = __builtin_elementwise_fma(d, d, s2);
                d = x3 - op[3]; s2 = __builtin_elementwise_fma(d, d, s2);
                float d2 = s2.x + s2.y + 1e-12f;
                Crow[t >> 1][t & 1] = fmaf(__builtin_amdgcn_sqrtf(d2), CSCALE, CBIAS);
                const f2* qp = (const f2*)(&sX[t * 8]);
                d = qp[0] - y0; s2 = d * d;
                d = qp[1] - y1; s2 = __builtin_elementwise_fma(d, d, s2);
                d = qp[2] - y2; s2 = __builtin_elementwise_fma(d, d, s2);
                d = qp[3] - y3; s2 = __builtin_elementwise_fma(d, d, s2);
                float e2 = s2.x + s2.y + 1e-12f;
                Ccol[t >> 1][t & 1] = fmaf(__builtin_amdgcn_sqrtf(e2), CSCALE, CBIAS);
            }
        }

        float ft = 0.0f, gt = 0.0f;

        // Phase A: 2 log-domain iterations (full 32-wide LSE per lane, no shfl)
        #pragma unroll 1
        for (int it = 0; it < 2; ++it) {
            {
                const float4* gp = (const float4*)sg;
                float4 G[8];
                #pragma unroll
                for (int r = 0; r < 8; ++r) G[r] = gp[r];
                f2 val[16], m2 = f2{-1e30f, -1e30f};
                #pragma unroll
                for (int r = 0; r < 8; ++r) {
                    val[2 * r]     = f2{G[r].x, G[r].y} + Crow[2 * r];
                    val[2 * r + 1] = f2{G[r].z, G[r].w} + Crow[2 * r + 1];
                    m2 = __builtin_elementwise_max(m2, val[2 * r]);
                    m2 = __builtin_elementwise_max(m2, val[2 * r + 1]);
                }
                float m = fmaxf(m2.x, m2.y);
                f2 mm = f2{m, m};
                float s0 = 0.0f, s1 = 0.0f;
                #pragma unroll
                for (int t2 = 0; t2 < 16; ++t2) {
                    f2 e = val[t2] - mm;
                    s0 += __builtin_amdgcn_exp2f(e.x);
                    s1 += __builtin_amdgcn_exp2f(e.y);
                }
                ft = -(m + __builtin_amdgcn_logf(s0 + s1));
            }
            sf[l] = ft;
            {
                const float4* fp = (const float4*)sf;
                float4 F[8];
                #pragma unroll
                for (int r = 0; r < 8; ++r) F[r] = fp[r];
                f2 val[16], m2 = f2{-1e30f, -1e30f};
                #pragma unroll
                for (int r = 0; r < 8; ++r) {
                    val[2 * r]     = f2{F[r].x, F[r].y} + Ccol[2 * r];
                    val[2 * r + 1] = f2{F[r].z, F[r].w} + Ccol[2 * r + 1];
                    m2 = __builtin_elementwise_max(m2, val[2 * r]);
                    m2 = __builtin_elementwise_max(m2, val[2 * r + 1]);
                }
                float m = fmaxf(m2.x, m2.y);
                f2 mm = f2{m, m};
                float s0 = 0.0f, s1 = 0.0f;
                #pragma unroll
                for (int t2 = 0; t2 < 16; ++t2) {
                    f2 e = val[t2] - mm;
                    s0 += __builtin_amdgcn_exp2f(e.x);
                    s1 += __builtin_amdgcn_exp2f(e.y);
                }
                gt = -(m + __builtin_amdgcn_logf(s0 + s1));
            }
            sg[l] = gt;
        }

        // Build K (row copy + col copy); C dies here.
        f2 KR[16], KC[16];
        {
            const float4* gp = (const float4*)sg;
            #pragma unroll
            for (int r = 0; r < 8; ++r) {
                float4 G = gp[r];
                f2 a0 = f2{G.x, G.y} + Crow[2 * r] + f2{ft, ft};
                f2 a1 = f2{G.z, G.w} + Crow[2 * r + 1] + f2{ft, ft};
                KR[2 * r].x     = __builtin_amdgcn_exp2f(a0.x);
                KR[2 * r].y     = __builtin_amdgcn_exp2f(a0.y);
                KR[2 * r + 1].x = __builtin_amdgcn_exp2f(a1.x);
                KR[2 * r + 1].y = __builtin_amdgcn_exp2f(a1.y);
            }
            const float4* fp = (const float4*)sf;
            #pragma unroll
            for (int r = 0; r < 8; ++r) {
                float4 F = fp[r];
                f2 a0 = f2{F.x, F.y} + Ccol[2 * r] + f2{gt, gt};
                f2 a1 = f2{F.z, F.w} + Ccol[2 * r + 1] + f2{gt, gt};
                KC[2 * r].x     = __builtin_amdgcn_exp2f(a0.x);
                KC[2 * r].y     = __builtin_amdgcn_exp2f(a0.y);
                KC[2 * r + 1].x = __builtin_amdgcn_exp2f(a1.x);
                KC[2 * r + 1].y = __builtin_amdgcn_exp2f(a1.y);
            }
        }
        sv[l] = 1.0f;
        float ureg = 1.0f, vreg = 1.0f;

        const int blens[5] = {6, 6, 12, 12, 12};   // 48 exp iters total
        #pragma unroll 1
        for (int blk = 0; blk < 5; ++blk) {
            int L = blens[blk];
            #pragma unroll 2
            for (int s6 = 0; s6 < L; ++s6) {
                // f-step: u_l = 1/(KR . v), full dot, no shfl
                {
                    const float4* vp = (const float4*)sv;
                    f2 acc0, acc1;
                    float4 A = vp[0];
                    acc0 = KR[0] * f2{A.x, A.y};
                    acc1 = KR[1] * f2{A.z, A.w};
                    #pragma unroll
                    for (int r = 1; r < 8; ++r) {
                        float4 B = vp[r];
                        acc0 = __builtin_elementwise_fma(KR[2 * r],     f2{B.x, B.y}, acc0);
                        acc1 = __builtin_elementwise_fma(KR[2 * r + 1], f2{B.z, B.w}, acc1);
                    }
                    f2 a = acc0 + acc1;
                    ureg = __builtin_amdgcn_rcpf(a.x + a.y);
                }
                su[l] = ureg;
                // g-step: v_l = 1/(KC . u)
                {
                    const float4* up = (const float4*)su;
                    f2 acc0, acc1;
                    float4 A = up[0];
                    acc0 = KC[0] * f2{A.x, A.y};
                    acc1 = KC[1] * f2{A.z, A.w};
                    #pragma unroll
                    for (int r = 1; r < 8; ++r) {
                        float4 B = up[r];
                        acc0 = __builtin_elementwise_fma(KC[2 * r],     f2{B.x, B.y}, acc0);
                        acc1 = __builtin_elementwise_fma(KC[2 * r + 1], f2{B.z, B.w}, acc1);
                    }
                    f2 a = acc0 + acc1;
                    vreg = __builtin_amdgcn_rcpf(a.x + a.y);
                }
                sv[l] = vreg;
            }
            if (blk < 4) {
                float df = __builtin_amdgcn_logf(ureg);
                float dg = __builtin_amdgcn_logf(vreg);
                ft += df;
                gt += dg;
                sf[l] = df;
                sg[l] = dg;
                // KR[j] *= exp2(df + dg_j); KC[i] *= exp2(dg + df_i)
                const float4* dgv = (const float4*)sg;
                #pragma unroll
                for (int r = 0; r < 8; ++r) {
                    float4 D = dgv[r];
                    f2 e0, e1;
                    e0.x = __builtin_amdgcn_exp2f(df + D.x);
                    e0.y = __builtin_amdgcn_exp2f(df + D.y);
                    e1.x = __builtin_amdgcn_exp2f(df + D.z);
                    e1.y = __builtin_amdgcn_exp2f(df + D.w);
                    KR[2 * r]     *= e0;
                    KR[2 * r + 1] *= e1;
                }
                const float4* dfv = (const float4*)sf;
                #pragma unroll
                for (int r = 0; r < 8; ++r) {
                    float4 D = dfv[r];
                    f2 e0, e1;
                    e0.x = __builtin_amdgcn_exp2f(dg + D.x);
                    e0.y = __builtin_amdgcn_exp2f(dg + D.y);
                    e1.x = __builtin_amdgcn_exp2f(dg + D.z);
                    e1.y = __builtin_amdgcn_exp2f(dg + D.w);
                    KC[2 * r]     *= e0;
                    KC[2 * r + 1] *= e1;
                }
                sv[l] = 1.0f;
                ureg = 1.0f;
                vreg = 1.0f;
            }
        }
        ft += __builtin_amdgcn_logf(ureg);
        gt += __builtin_amdgcn_logf(vreg);

        // OT = eps*ln2*(sum_l f_l + g_l)/32; reduce within half-wave
        float v = ft + gt;
        #pragma unroll
        for (int off = 16; off > 0; off >>= 1) v += __shfl_xor(v, off);
        if (l == 0) {
            float cost = v * (EPS_F * LN2_F / 32.0f);
            unsafeAtomicAdd(&dist[p], cost);
        }
    }
}

// ------------------------------------------------------------------ finalize
__global__ void k_finalize(const float* __restrict__ dist,
                           const float* __restrict__ gd, float* __restrict__ out) {
    __shared__ float red[256];
    float s = 0.0f;
    for (int i = threadIdx.x; i < N_PAIRS; i += 256) {
        float g = gd[i];
        s += fabsf(dist[i] - g) / g;
    }
    red[threadIdx.x] = s;
    __syncthreads();
    for (int o = 128; o > 0; o >>= 1) {
        if (threadIdx.x < o) red[threadIdx.x] += red[threadIdx.x + o];
        __syncthreads();
    }
    if (threadIdx.x == 0) out[0] = red[0] * (1.0f / N_PAIRS);
}

// -------------------------------------------------------------------- launch
extern "C" void kernel_launch(void* const* d_in, const int* in_sizes, int n_in,
                              void* d_out, int out_size, void* d_ws, size_t ws_size,
                              hipStream_t stream) {
    const float* x    = (const float*)d_in[0];   // [50000,128]
    const float* W    = (const float*)d_in[1];   // [128,256]
    const int*   eidx = (const int*)d_in[2];     // [2,800000]
    const int*   pair = (const int*)d_in[3];     // [2,8192] flat = 16384 slots
    const float* gd   = (const float*)d_in[4];   // [8192]

    char* ws = (char*)d_ws;
    size_t off = 0;
    int*   cnt    = (int*)  (ws + off); off += (size_t)N_NODES * 4;
    int*   flags  = (int*)  (ws + off); off += (size_t)N_NODES * 4;
    float* dist   = (float*)(ws + off); off += (size_t)N_PAIRS * 4;
    size_t zero_bytes = off;                     // cnt+flags+dist contiguous
    int*   bucket = (int*)  (ws + off); off += (size_t)N_NODES * CAP * 4; // 12.8 MB
    float* Z      = (float*)(ws + off); off += (size_t)N_SLOTS * 256 * 4; // 16.8 MB

    hipMemsetAsync(d_ws, 0, zero_bytes, stream);
    k_mark    <<<(N_SLOTS + 255) / 256, 256, 0, stream>>>(pair, flags);
    k_scatter <<<N_EDGES / 256, 256, 0, stream>>>(eidx, flags, cnt, bucket);
    k_gemm    <<<N_SLOTS / 16, 256, 0, stream>>>(pair, x, cnt, bucket, W, Z);
    k_sinkhorn<<<6144, 128, 0, stream>>>(Z, dist);
    k_finalize<<<1, 256, 0, stream>>>(dist, gd, (float*)d_out);
}